// Round 2
// baseline (406.355 us; speedup 1.0000x reference)
//
#include <hip/hip_runtime.h>

#define BB 32
#define VV 48
#define CC 24
#define AA 6
#define NCODES 10001
#define DD 128
#define HH 128
#define OUTN 167
#define G3 384  // 3*H

__device__ __forceinline__ float fast_tanh(float x) {
    return 1.0f - 2.0f / (1.0f + __expf(2.0f * x));
}
__device__ __forceinline__ float fast_sigmoid(float x) {
    return 1.0f / (1.0f + __expf(-x));
}
__device__ __forceinline__ float dot4(float4 a, float4 b) {
    return a.x * b.x + a.y * b.y + a.z * b.z + a.w * b.w;
}

// K1: P1[c,e] = sum_d emb[c,d]*W[e,d]; P2[c,e] = sum_d emb[c,d]*W[e,128+d]
__global__ __launch_bounds__(256) void k_precompute(
    const float* __restrict__ emb, const float* __restrict__ w_basic,
    float* __restrict__ P1, float* __restrict__ P2, int nrows)
{
    __shared__ __align__(16) float embs[8][128];
    int row0 = blockIdx.x * 8;
    int t = threadIdx.x;
    {
        int r = t >> 5;
        int row = row0 + r;
        float4 v = make_float4(0.f, 0.f, 0.f, 0.f);
        if (row < nrows) v = ((const float4*)emb)[row * 32 + (t & 31)];
        ((float4*)embs)[t] = v;
    }
    __syncthreads();
    int e = t & 127, sel = t >> 7;
    const float4* wrow4 = (const float4*)(w_basic + e * 256 + sel * 128);
    float acc[8] = {0, 0, 0, 0, 0, 0, 0, 0};
#pragma unroll
    for (int d4 = 0; d4 < 32; ++d4) {
        float4 wv = wrow4[d4];
#pragma unroll
        for (int r = 0; r < 8; ++r) {
            float4 ev = ((const float4*)embs[r])[d4];
            acc[r] += dot4(ev, wv);
        }
    }
    float* dst = sel ? P2 : P1;
#pragma unroll
    for (int r = 0; r < 8; ++r) {
        int row = row0 + r;
        if (row < nrows) dst[row * 128 + e] = acc[r];
    }
}

// K2: attention + visit embedding x[bv,128]
__global__ __launch_bounds__(256) void k_attention(
    const int* __restrict__ seqs, const int* __restrict__ ancestors,
    const float* __restrict__ amask, const float* __restrict__ emb,
    const float* __restrict__ P1, const float* __restrict__ P2,
    const float* __restrict__ u_w, const float* __restrict__ u_b,
    float* __restrict__ x_out)
{
    __shared__ __align__(16) float u_s[128];
    __shared__ float sc_s[144];
    __shared__ float m_s[144];
    __shared__ int   anc_s[144];
    __shared__ float attn_s[144];
    __shared__ float sum_s[24];
    __shared__ float xred[256];
    int bv = blockIdx.x;
    int t = threadIdx.x;
    if (t < 128) u_s[t] = u_w[t];
    __syncthreads();
    float ub = u_b[0];
    int g = t >> 2, l = t & 3;
    for (int p = g; p < CC * AA; p += 64) {
        int c = p / AA, a = p - c * AA;
        int sidx = bv * CC + c;
        int s_code = seqs[sidx];
        int aidx = sidx * AA + a;
        int anc = ancestors[aidx];
        float m = amask[aidx];
        const float4* p14 = (const float4*)(P1 + s_code * 128);
        const float4* p24 = (const float4*)(P2 + anc * 128);
        const float4* u4 = (const float4*)u_s;
        float partial = 0.0f;
        int e4 = l * 8;
#pragma unroll
        for (int j = 0; j < 8; ++j) {
            float4 av = p14[e4 + j];
            float4 bv_ = p24[e4 + j];
            float4 uv = u4[e4 + j];
            partial += fast_tanh(m * (av.x + bv_.x)) * uv.x;
            partial += fast_tanh(m * (av.y + bv_.y)) * uv.y;
            partial += fast_tanh(m * (av.z + bv_.z)) * uv.z;
            partial += fast_tanh(m * (av.w + bv_.w)) * uv.w;
        }
        partial += __shfl_xor(partial, 1);
        partial += __shfl_xor(partial, 2);
        if (l == 0) {
            sc_s[p] = partial + ub;
            m_s[p] = m;
            anc_s[p] = anc;
        }
    }
    __syncthreads();
    if (t < CC * AA) attn_s[t] = __expf(sc_s[t]) * m_s[t];
    __syncthreads();
    if (t < CC) {
        float s = 0.0f;
#pragma unroll
        for (int a = 0; a < AA; ++a) s += attn_s[t * AA + a];
        sum_s[t] = (s == 0.0f) ? -1.0f : s;
    }
    __syncthreads();
    if (t < CC * AA) attn_s[t] = attn_s[t] / sum_s[t / AA];
    __syncthreads();
    int e = t & 127, hc = t >> 7;
    float acc = 0.0f;
    for (int c = hc * 12; c < hc * 12 + 12; ++c) {
#pragma unroll
        for (int a = 0; a < AA; ++a) {
            int p = c * AA + a;
            acc += attn_s[p] * emb[anc_s[p] * 128 + e];
        }
    }
    xred[t] = acc;
    __syncthreads();
    if (t < 128) {
        x_out[bv * 128 + t] = fast_tanh(xred[t] + xred[t + 128]);
    }
}

// K3: gi[bv,o] = sum_d x[bv,d]*Wih[o,d] + bih[o]
__global__ __launch_bounds__(384) void k_gi(
    const float* __restrict__ x, const float* __restrict__ wih,
    const float* __restrict__ bih, float* __restrict__ gi)
{
    __shared__ __align__(16) float xs[8][128];
    int row0 = blockIdx.x * 8;
    int t = threadIdx.x;
    for (int i = t; i < 8 * 32; i += 384) {
        ((float4*)xs)[i] = ((const float4*)x)[row0 * 32 + i];
    }
    __syncthreads();
    const float4* wrow4 = (const float4*)(wih + t * 128);
    float acc[8] = {0, 0, 0, 0, 0, 0, 0, 0};
#pragma unroll
    for (int d4 = 0; d4 < 32; ++d4) {
        float4 wv = wrow4[d4];
#pragma unroll
        for (int r = 0; r < 8; ++r) {
            float4 xv = ((const float4*)xs[r])[d4];
            acc[r] += dot4(xv, wv);
        }
    }
    float bb = bih[t];
#pragma unroll
    for (int r = 0; r < 8; ++r) gi[(row0 + r) * G3 + t] = acc[r] + bb;
}

// K4: sequential GRU, 256 threads, Whh in registers, 1 barrier/step.
__global__ __launch_bounds__(256, 1) void k_gru(
    const float* __restrict__ gi, const float* __restrict__ whh,
    const float* __restrict__ bhh, const int* __restrict__ length,
    const float* __restrict__ out_w, const float* __restrict__ out_b,
    float* __restrict__ out)
{
    __shared__ __align__(16) float hs[2][128];
    __shared__ __align__(16) float ctxs[128];
    int b = blockIdx.x;
    int t = threadIdx.x;
    int o = t >> 1, half = t & 1;

    float4 wr[16], wz[16], wn[16];
    {
        const float4* wr4 = (const float4*)(whh + o * 128 + half * 64);
        const float4* wz4 = (const float4*)(whh + (128 + o) * 128 + half * 64);
        const float4* wn4 = (const float4*)(whh + (256 + o) * 128 + half * 64);
#pragma unroll
        for (int j = 0; j < 16; ++j) {
            wr[j] = wr4[j];
            wz[j] = wz4[j];
            wn[j] = wn4[j];
        }
    }
    float bhr = 0.f, bhz = 0.f, bhn = 0.f;
    if (half == 0) {
        bhr = bhh[o];
        bhz = bhh[128 + o];
        bhn = bhh[256 + o];
    }
    if (t < 128) hs[0][t] = 0.0f;
    int len = length[b];
    float ctx = 0.0f;
    __syncthreads();

    const float* gib = gi + b * VV * G3;
    int cur = 0;
    for (int v = 0; v < VV; ++v) {
        float gir = 0.f, giz = 0.f, gin = 0.f;
        if (half == 0) {
            const float* g = gib + v * G3;
            gir = g[o];
            giz = g[128 + o];
            gin = g[256 + o];
        }
        const float4* h4 = ((const float4*)hs[cur]) + half * 16;
        float ar0 = 0.f, ar1 = 0.f, az0 = 0.f, az1 = 0.f, an0 = 0.f, an1 = 0.f;
#pragma unroll
        for (int j = 0; j < 16; j += 2) {
            float4 h0 = h4[j];
            float4 h1 = h4[j + 1];
            ar0 += dot4(wr[j], h0);
            ar1 += dot4(wr[j + 1], h1);
            az0 += dot4(wz[j], h0);
            az1 += dot4(wz[j + 1], h1);
            an0 += dot4(wn[j], h0);
            an1 += dot4(wn[j + 1], h1);
        }
        float ar = ar0 + ar1;
        float az = az0 + az1;
        float an = an0 + an1;
        ar += __shfl_xor(ar, 1);
        az += __shfl_xor(az, 1);
        an += __shfl_xor(an, 1);
        if (half == 0) {
            float r = fast_sigmoid(gir + ar + bhr);
            float z = fast_sigmoid(giz + az + bhz);
            float n = fast_tanh(gin + r * (an + bhn));
            float hold = hs[cur][o];
            float hnew = (1.0f - z) * n + z * hold;
            hs[cur ^ 1][o] = hnew;
            if (v < len) ctx += hnew;
        }
        cur ^= 1;
        __syncthreads();
    }

    if (half == 0) ctxs[o] = ctx;
    __syncthreads();
    if (t < OUTN) {
        const float4* w4 = (const float4*)(out_w + t * 128);
        const float4* c4 = (const float4*)ctxs;
        float a0 = 0.f, a1 = 0.f;
#pragma unroll
        for (int j = 0; j < 32; j += 2) {
            a0 += dot4(w4[j], c4[j]);
            a1 += dot4(w4[j + 1], c4[j + 1]);
        }
        out[b * OUTN + t] = fast_sigmoid(a0 + a1 + out_b[t]);
    }
}

extern "C" void kernel_launch(void* const* d_in, const int* in_sizes, int n_in,
                              void* d_out, int out_size, void* d_ws, size_t ws_size,
                              hipStream_t stream) {
    const int*   seqs      = (const int*)d_in[0];
    const int*   ancestors = (const int*)d_in[1];
    const int*   length    = (const int*)d_in[2];
    const float* amask     = (const float*)d_in[3];
    const float* emb       = (const float*)d_in[4];
    const float* w_basic   = (const float*)d_in[5];
    const float* u_w       = (const float*)d_in[6];
    const float* u_b       = (const float*)d_in[7];
    const float* wih       = (const float*)d_in[8];
    const float* whh       = (const float*)d_in[9];
    const float* bih       = (const float*)d_in[10];
    const float* bhh       = (const float*)d_in[11];
    const float* out_w     = (const float*)d_in[12];
    const float* out_b     = (const float*)d_in[13];
    float* out = (float*)d_out;

    float* ws = (float*)d_ws;
    float* P1 = ws;                       // [10001,128]
    float* P2 = P1 + NCODES * 128;        // [10001,128]
    float* x  = P2 + NCODES * 128;        // [1536,128]
    float* gi = x + BB * VV * 128;        // [1536,384]

    k_precompute<<<(NCODES + 7) / 8, 256, 0, stream>>>(emb, w_basic, P1, P2, NCODES);
    k_attention<<<BB * VV, 256, 0, stream>>>(seqs, ancestors, amask, emb, P1, P2, u_w, u_b, x);
    k_gi<<<(BB * VV) / 8, 384, 0, stream>>>(x, wih, bih, gi);
    k_gru<<<BB, 256, 0, stream>>>(gi, whh, bhh, length, out_w, out_b, out);
}

// Round 3
// 134.773 us; speedup vs baseline: 3.0151x; 3.0151x over previous
//
#include <hip/hip_runtime.h>

#define BB 32
#define VV 48
#define CC 24
#define AA 6
#define NCODES 10001
#define DD 128
#define HH 128
#define OUTN 167
#define G3 384  // 3*H

__device__ __forceinline__ float fast_tanh(float x) {
    return 1.0f - 2.0f / (1.0f + __expf(2.0f * x));
}
__device__ __forceinline__ float fast_sigmoid(float x) {
    return 1.0f / (1.0f + __expf(-x));
}
__device__ __forceinline__ float dot4(float4 a, float4 b) {
    return a.x * b.x + a.y * b.y + a.z * b.z + a.w * b.w;
}

// K1: P1[c,e] = sum_d emb[c,d]*W[e,d]; P2[c,e] = sum_d emb[c,d]*W[e,128+d]
// 16 rows/block; LDS emb reads are block-uniform broadcasts (conflict-free).
// unroll capped at 2 so only 2 w-float4 are in flight (round-2 spill fix).
__global__ __launch_bounds__(256, 4) void k_precompute(
    const float* __restrict__ emb, const float* __restrict__ w_basic,
    float* __restrict__ P1, float* __restrict__ P2, int nrows)
{
    __shared__ float4 embs4[16 * 32];
    int row0 = blockIdx.x * 16;
    int t = threadIdx.x;
    for (int i = t; i < 512; i += 256) {
        int r = i >> 5;
        int row = row0 + r;
        float4 v = make_float4(0.f, 0.f, 0.f, 0.f);
        if (row < nrows) v = ((const float4*)emb)[row * 32 + (i & 31)];
        embs4[i] = v;
    }
    __syncthreads();
    int e = t & 127, sel = t >> 7;
    const float4* wrow4 = (const float4*)(w_basic + e * 256 + sel * 128);
    float acc[16] = {};
#pragma unroll 2
    for (int d4 = 0; d4 < 32; ++d4) {
        float4 wv = wrow4[d4];
#pragma unroll
        for (int r = 0; r < 16; ++r) {
            acc[r] += dot4(embs4[r * 32 + d4], wv);
        }
    }
    float* dst = sel ? P2 : P1;
#pragma unroll
    for (int r = 0; r < 16; ++r) {
        int row = row0 + r;
        if (row < nrows) dst[row * 128 + e] = acc[r];
    }
}

// K2: attention + visit embedding x[bv,128]
__global__ __launch_bounds__(256) void k_attention(
    const int* __restrict__ seqs, const int* __restrict__ ancestors,
    const float* __restrict__ amask, const float* __restrict__ emb,
    const float* __restrict__ P1, const float* __restrict__ P2,
    const float* __restrict__ u_w, const float* __restrict__ u_b,
    float* __restrict__ x_out)
{
    __shared__ __align__(16) float u_s[128];
    __shared__ float sc_s[144];
    __shared__ float m_s[144];
    __shared__ int   anc_s[144];
    __shared__ float attn_s[144];
    __shared__ float sum_s[24];
    __shared__ float xred[256];
    int bv = blockIdx.x;
    int t = threadIdx.x;
    if (t < 128) u_s[t] = u_w[t];
    __syncthreads();
    float ub = u_b[0];
    int g = t >> 2, l = t & 3;
    for (int p = g; p < CC * AA; p += 64) {
        int c = p / AA, a = p - c * AA;
        int sidx = bv * CC + c;
        int s_code = seqs[sidx];
        int aidx = sidx * AA + a;
        int anc = ancestors[aidx];
        float m = amask[aidx];
        const float4* p14 = (const float4*)(P1 + s_code * 128);
        const float4* p24 = (const float4*)(P2 + anc * 128);
        const float4* u4 = (const float4*)u_s;
        float partial = 0.0f;
        int e4 = l * 8;
#pragma unroll 2
        for (int j = 0; j < 8; ++j) {
            float4 av = p14[e4 + j];
            float4 bv_ = p24[e4 + j];
            float4 uv = u4[e4 + j];
            partial += fast_tanh(m * (av.x + bv_.x)) * uv.x;
            partial += fast_tanh(m * (av.y + bv_.y)) * uv.y;
            partial += fast_tanh(m * (av.z + bv_.z)) * uv.z;
            partial += fast_tanh(m * (av.w + bv_.w)) * uv.w;
        }
        partial += __shfl_xor(partial, 1);
        partial += __shfl_xor(partial, 2);
        if (l == 0) {
            sc_s[p] = partial + ub;
            m_s[p] = m;
            anc_s[p] = anc;
        }
    }
    __syncthreads();
    if (t < CC * AA) attn_s[t] = __expf(sc_s[t]) * m_s[t];
    __syncthreads();
    if (t < CC) {
        float s = 0.0f;
#pragma unroll
        for (int a = 0; a < AA; ++a) s += attn_s[t * AA + a];
        sum_s[t] = (s == 0.0f) ? -1.0f : s;
    }
    __syncthreads();
    if (t < CC * AA) attn_s[t] = attn_s[t] / sum_s[t / AA];
    __syncthreads();
    int e = t & 127, hc = t >> 7;
    float acc = 0.0f;
    for (int c = hc * 12; c < hc * 12 + 12; ++c) {
#pragma unroll
        for (int a = 0; a < AA; ++a) {
            int p = c * AA + a;
            acc += attn_s[p] * emb[anc_s[p] * 128 + e];
        }
    }
    xred[t] = acc;
    __syncthreads();
    if (t < 128) {
        x_out[bv * 128 + t] = fast_tanh(xred[t] + xred[t + 128]);
    }
}

// K3: gi[bv,o] = sum_d x[bv,d]*Wih[o,d] + bih[o]; unroll capped (spill fix)
__global__ __launch_bounds__(384, 2) void k_gi(
    const float* __restrict__ x, const float* __restrict__ wih,
    const float* __restrict__ bih, float* __restrict__ gi)
{
    __shared__ __align__(16) float xs[8][128];
    int row0 = blockIdx.x * 8;
    int t = threadIdx.x;
    for (int i = t; i < 8 * 32; i += 384) {
        ((float4*)xs)[i] = ((const float4*)x)[row0 * 32 + i];
    }
    __syncthreads();
    const float4* wrow4 = (const float4*)(wih + t * 128);
    float acc[8] = {0, 0, 0, 0, 0, 0, 0, 0};
#pragma unroll 2
    for (int d4 = 0; d4 < 32; ++d4) {
        float4 wv = wrow4[d4];
#pragma unroll
        for (int r = 0; r < 8; ++r) {
            float4 xv = ((const float4*)xs[r])[d4];
            acc[r] += dot4(xv, wv);
        }
    }
    float bb = bih[t];
#pragma unroll
    for (int r = 0; r < 8; ++r) gi[(row0 + r) * G3 + t] = acc[r] + bb;
}

// K4: sequential GRU, 256 threads, Whh in registers, 1 barrier/step.
__global__ __launch_bounds__(256, 1) void k_gru(
    const float* __restrict__ gi, const float* __restrict__ whh,
    const float* __restrict__ bhh, const int* __restrict__ length,
    const float* __restrict__ out_w, const float* __restrict__ out_b,
    float* __restrict__ out)
{
    __shared__ __align__(16) float hs[2][128];
    __shared__ __align__(16) float ctxs[128];
    int b = blockIdx.x;
    int t = threadIdx.x;
    int o = t >> 1, half = t & 1;

    float4 wr[16], wz[16], wn[16];
    {
        const float4* wr4 = (const float4*)(whh + o * 128 + half * 64);
        const float4* wz4 = (const float4*)(whh + (128 + o) * 128 + half * 64);
        const float4* wn4 = (const float4*)(whh + (256 + o) * 128 + half * 64);
#pragma unroll
        for (int j = 0; j < 16; ++j) {
            wr[j] = wr4[j];
            wz[j] = wz4[j];
            wn[j] = wn4[j];
        }
    }
    float bhr = 0.f, bhz = 0.f, bhn = 0.f;
    if (half == 0) {
        bhr = bhh[o];
        bhz = bhh[128 + o];
        bhn = bhh[256 + o];
    }
    if (t < 128) hs[0][t] = 0.0f;
    int len = length[b];
    float ctx = 0.0f;
    __syncthreads();

    const float* gib = gi + b * VV * G3;
    int cur = 0;
    for (int v = 0; v < VV; ++v) {
        float gir = 0.f, giz = 0.f, gin = 0.f;
        if (half == 0) {
            const float* g = gib + v * G3;
            gir = g[o];
            giz = g[128 + o];
            gin = g[256 + o];
        }
        const float4* h4 = ((const float4*)hs[cur]) + half * 16;
        float ar0 = 0.f, ar1 = 0.f, az0 = 0.f, az1 = 0.f, an0 = 0.f, an1 = 0.f;
#pragma unroll
        for (int j = 0; j < 16; j += 2) {
            float4 h0 = h4[j];
            float4 h1 = h4[j + 1];
            ar0 += dot4(wr[j], h0);
            ar1 += dot4(wr[j + 1], h1);
            az0 += dot4(wz[j], h0);
            az1 += dot4(wz[j + 1], h1);
            an0 += dot4(wn[j], h0);
            an1 += dot4(wn[j + 1], h1);
        }
        float ar = ar0 + ar1;
        float az = az0 + az1;
        float an = an0 + an1;
        ar += __shfl_xor(ar, 1);
        az += __shfl_xor(az, 1);
        an += __shfl_xor(an, 1);
        if (half == 0) {
            float r = fast_sigmoid(gir + ar + bhr);
            float z = fast_sigmoid(giz + az + bhz);
            float n = fast_tanh(gin + r * (an + bhn));
            float hold = hs[cur][o];
            float hnew = (1.0f - z) * n + z * hold;
            hs[cur ^ 1][o] = hnew;
            if (v < len) ctx += hnew;
        }
        cur ^= 1;
        __syncthreads();
    }

    if (half == 0) ctxs[o] = ctx;
    __syncthreads();
    if (t < OUTN) {
        const float4* w4 = (const float4*)(out_w + t * 128);
        const float4* c4 = (const float4*)ctxs;
        float a0 = 0.f, a1 = 0.f;
#pragma unroll 2
        for (int j = 0; j < 32; j += 2) {
            a0 += dot4(w4[j], c4[j]);
            a1 += dot4(w4[j + 1], c4[j + 1]);
        }
        out[b * OUTN + t] = fast_sigmoid(a0 + a1 + out_b[t]);
    }
}

extern "C" void kernel_launch(void* const* d_in, const int* in_sizes, int n_in,
                              void* d_out, int out_size, void* d_ws, size_t ws_size,
                              hipStream_t stream) {
    const int*   seqs      = (const int*)d_in[0];
    const int*   ancestors = (const int*)d_in[1];
    const int*   length    = (const int*)d_in[2];
    const float* amask     = (const float*)d_in[3];
    const float* emb       = (const float*)d_in[4];
    const float* w_basic   = (const float*)d_in[5];
    const float* u_w       = (const float*)d_in[6];
    const float* u_b       = (const float*)d_in[7];
    const float* wih       = (const float*)d_in[8];
    const float* whh       = (const float*)d_in[9];
    const float* bih       = (const float*)d_in[10];
    const float* bhh       = (const float*)d_in[11];
    const float* out_w     = (const float*)d_in[12];
    const float* out_b     = (const float*)d_in[13];
    float* out = (float*)d_out;

    float* ws = (float*)d_ws;
    float* P1 = ws;                       // [10001,128]
    float* P2 = P1 + NCODES * 128;        // [10001,128]
    float* x  = P2 + NCODES * 128;        // [1536,128]
    float* gi = x + BB * VV * 128;        // [1536,384]

    k_precompute<<<(NCODES + 15) / 16, 256, 0, stream>>>(emb, w_basic, P1, P2, NCODES);
    k_attention<<<BB * VV, 256, 0, stream>>>(seqs, ancestors, amask, emb, P1, P2, u_w, u_b, x);
    k_gi<<<(BB * VV) / 8, 384, 0, stream>>>(x, wih, bih, gi);
    k_gru<<<BB, 256, 0, stream>>>(gi, whh, bhh, length, out_w, out_b, out);
}